// Round 11
// baseline (1807.536 us; speedup 1.0000x reference)
//
#include <hip/hip_runtime.h>
#include <math.h>

#define NN 50000
#define FINN 64
#define HD 128
#define EE 800000
#define TT 8
#define PP 250000
#define DD 500000
#define GG 20000
#define VV 2000
#define OO 2

typedef short short8 __attribute__((ext_vector_type(8)));
typedef float f32x4 __attribute__((ext_vector_type(4)));

__device__ __forceinline__ unsigned short f2bf(float f) {
    unsigned int u = __float_as_uint(f);
    u += 0x7fffu + ((u >> 16) & 1u);   // round-to-nearest-even
    return (unsigned short)(u >> 16);
}
__device__ __forceinline__ float bf2f(unsigned short u) {
    return __uint_as_float(((unsigned int)u) << 16);
}

struct us8 { unsigned short v[8]; };

// ------------------------------------------------------------------
__global__ void count_k(const int* __restrict__ idx, int* __restrict__ counts, int n) {
    int i = blockIdx.x * blockDim.x + threadIdx.x;
    if (i < n) atomicAdd(&counts[idx[i]], 1);
}

// ---- 3-phase parallel exclusive scan for edge CSR rowptr ----
__global__ void blk_sum_k(const int* __restrict__ counts, int n, int* __restrict__ bsum) {
    __shared__ int buf[256];
    int t = threadIdx.x, i = blockIdx.x * 256 + t;
    buf[t] = (i < n) ? counts[i] : 0;
    __syncthreads();
    for (int off = 128; off > 0; off >>= 1) {
        if (t < off) buf[t] += buf[t + off];
        __syncthreads();
    }
    if (t == 0) bsum[blockIdx.x] = buf[0];
}

__global__ void scan_small_k(const int* __restrict__ bsum, int nb, int* __restrict__ boff) {
    __shared__ int buf[256];
    int t = threadIdx.x;
    int v = (t < nb) ? bsum[t] : 0;
    buf[t] = v;
    __syncthreads();
    for (int off = 1; off < 256; off <<= 1) {
        int u = (t >= off) ? buf[t - off] : 0;
        __syncthreads();
        buf[t] += u;
        __syncthreads();
    }
    if (t < nb) boff[t] = buf[t] - v;
}

__global__ void rowptr_fill_k(const int* __restrict__ counts, const int* __restrict__ boff,
                              int n, int* __restrict__ rowptr, int total) {
    __shared__ int buf[256];
    int t = threadIdx.x, i = blockIdx.x * 256 + t;
    int v = (i < n) ? counts[i] : 0;
    buf[t] = v;
    __syncthreads();
    for (int off = 1; off < 256; off <<= 1) {
        int u = (t >= off) ? buf[t - off] : 0;
        __syncthreads();
        buf[t] += u;
        __syncthreads();
    }
    if (i < n) rowptr[i] = boff[blockIdx.x] + buf[t] - v;
    if (i == 0) rowptr[n] = total;
}

// rowptr for SORTED arrays: rowptr[i] = lower_bound(arr, i), i in [0, m]
__global__ void lb_rowptr_k(const int* __restrict__ arr, int n, int* __restrict__ rowptr, int m) {
    int i = blockIdx.x * blockDim.x + threadIdx.x;
    if (i > m) return;
    int lo = 0, hi = n;
    while (lo < hi) {
        int mid = (lo + hi) >> 1;
        if (arr[mid] < i) lo = mid + 1; else hi = mid;
    }
    rowptr[i] = lo;
}

__global__ void fill_csr_k(const int* __restrict__ esrc, const int* __restrict__ edst,
                           const int* __restrict__ rowptr, int* __restrict__ cursor,
                           int* __restrict__ outi, int n) {
    int e = blockIdx.x * blockDim.x + threadIdx.x;
    if (e < n) {
        int d = edst[e];
        int pos = atomicAdd(&cursor[d], 1);
        outi[rowptr[d] + pos] = esrc[e];
    }
}

// ------------------------------------------------------------------
// t-bucket permutation
__global__ void hist9_k(const int* __restrict__ t_idx, int* __restrict__ hist) {
    __shared__ int l[9];
    if (threadIdx.x < 9) l[threadIdx.x] = 0;
    __syncthreads();
    int p = blockIdx.x * 256 + threadIdx.x;
    if (p < PP) atomicAdd(&l[t_idx[p]], 1);
    __syncthreads();
    if (threadIdx.x < 9) atomicAdd(&hist[threadIdx.x], l[threadIdx.x]);
}

__global__ void scan9_k(const int* __restrict__ hist, int* __restrict__ boff9) {
    if (threadIdx.x == 0) {
        int a = 0;
        for (int i = 0; i < 9; ++i) { boff9[i] = a; a += hist[i]; }
    }
}

__global__ void bucket_perm_k(const int* __restrict__ t_idx, const int* __restrict__ boff9,
                              int* __restrict__ cursor9, int* __restrict__ pperm) {
    __shared__ int lcnt[9];
    __shared__ int lbase[9];
    int tid = threadIdx.x;
    int p = blockIdx.x * 256 + tid;
    if (tid < 9) lcnt[tid] = 0;
    __syncthreads();
    int t = 0, lr = 0;
    bool ok = p < PP;
    if (ok) {
        t = t_idx[p];
        lr = atomicAdd(&lcnt[t], 1);
    }
    __syncthreads();
    if (tid < 9) lbase[tid] = atomicAdd(&cursor9[tid], lcnt[tid]);
    __syncthreads();
    if (ok) pperm[boff9[t] + lbase[t] + lr] = p;
}

// ------------------------------------------------------------------
// fused prep: x->bf16, both mp weight transposes, Wd1 transpose
__global__ void prep_k(const float* __restrict__ x,
                       const float* __restrict__ Wes, const float* __restrict__ Wen,
                       const float* __restrict__ W2s, const float* __restrict__ W2n,
                       const float* __restrict__ Wd1,
                       unsigned short* __restrict__ xb, unsigned short* __restrict__ wenc_t,
                       unsigned short* __restrict__ w2_t, unsigned short* __restrict__ wd1t) {
    int i = blockIdx.x * 256 + threadIdx.x;
    if (i < NN * FINN) xb[i] = f2bf(x[i]);
    if (i < HD * 2 * FINN) {
        int c = i / (2 * FINN), k = i - c * (2 * FINN);
        wenc_t[i] = f2bf((k < FINN) ? Wes[k * HD + c] : Wen[(k - FINN) * HD + c]);
    }
    if (i < HD * 2 * HD) {
        int c = i / (2 * HD), k = i - c * (2 * HD);
        w2_t[i] = f2bf((k < HD) ? W2s[k * HD + c] : W2n[(k - HD) * HD + c]);
    }
    if (i < 384 * 384) {
        int n = i / 384, k = i - n * 384;
        wd1t[i] = f2bf(Wd1[k * 384 + n]);
    }
}

// ------------------------------------------------------------------
// column-sliced mean-aggregation, ONE PASS PER LAUNCH: covers cols
// [pass*32, pass*32+32).  The 3.2MB slice fits each XCD's 4MB L2, and the
// kernel-boundary drain between passes keeps only one slice live at a time.
// 16 edge-chains per wave (4 lanes x us8 = 64B per edge).
template <int KIN>
__launch_bounds__(256)
__global__ void aggs_k(const unsigned short* __restrict__ h, const int* __restrict__ rowptr,
                       const int* __restrict__ csr_src, unsigned short* __restrict__ aggout,
                       int pass) {
    int node = blockIdx.x * 4 + (threadIdx.x >> 6);
    int lane = threadIdx.x & 63;
    int sub = lane >> 2;                   // 16 edge-chains per wave
    int fl  = lane & 3;                    // 4 lanes x us8 = 32 cols
    int col0 = pass * 32;
    if (node >= NN) return;
    int s = rowptr[node], e = rowptr[node + 1];
    float acc[8] = {};
    int i = s + sub;
    int src_next = (i < e) ? csr_src[i] : 0;
    for (; i < e; i += 16) {
        int src = src_next;
        int in = i + 16;
        if (in < e) src_next = csr_src[in];
        us8 v = *(const us8*)&h[(size_t)src * KIN + col0 + fl * 8];
#pragma unroll
        for (int j = 0; j < 8; ++j) acc[j] += bf2f(v.v[j]);
    }
#pragma unroll
    for (int m = 4; m < 64; m <<= 1)
#pragma unroll
        for (int j = 0; j < 8; ++j) acc[j] += __shfl_xor(acc[j], m);
    if (sub == 0) {
        float d = fmaxf((float)(e - s), 1.f);
        us8 o;
#pragma unroll
        for (int j = 0; j < 8; ++j) o.v[j] = f2bf(acc[j] / d);
        *(us8*)&aggout[(size_t)node * KIN + col0 + fl * 8] = o;
    }
}

// ------------------------------------------------------------------
// h_out = relu([hin | agg] @ Wt^T + b), bf16 MFMA, no LDS (R4-proven).
__launch_bounds__(256)
__global__ void mp_mfma_k(const unsigned short* __restrict__ hin,
                          const unsigned short* __restrict__ aggin,
                          const unsigned short* __restrict__ Wt,
                          const float* __restrict__ bias,
                          unsigned short* __restrict__ hout, int Kin) {
    int tid = threadIdx.x;
    int lane = tid & 63, w = tid >> 6;
    int cc = lane & 15, g = lane >> 4;
    int K = 2 * Kin;
    int rowA = blockIdx.x * 64 + w * 16 + cc;
    bool rowok = rowA < NN;
    const unsigned short* hrow = hin + (size_t)rowA * Kin;
    const unsigned short* arow = aggin + (size_t)rowA * Kin;

    f32x4 acc[8];
#pragma unroll
    for (int t = 0; t < 8; ++t) acc[t] = (f32x4){0.f, 0.f, 0.f, 0.f};

    for (int k0 = 0; k0 < K; k0 += 32) {
        int k = k0 + g * 8;
        short8 a = {0, 0, 0, 0, 0, 0, 0, 0};
        if (rowok)
            a = *(const short8*)((k < Kin) ? (hrow + k) : (arow + (k - Kin)));
#pragma unroll
        for (int t = 0; t < 8; ++t) {
            short8 b = *(const short8*)&Wt[(size_t)(t * 16 + cc) * K + k];
            acc[t] = __builtin_amdgcn_mfma_f32_16x16x32_bf16(a, b, acc[t], 0, 0, 0);
        }
    }
#pragma unroll
    for (int t = 0; t < 8; ++t) {
        int col = t * 16 + cc;
        float b1 = bias[col];
#pragma unroll
        for (int r = 0; r < 4; ++r) {
            int grow = blockIdx.x * 64 + w * 16 + g * 4 + r;
            if (grow < NN)
                hout[(size_t)grow * HD + col] = f2bf(fmaxf(acc[t][r] + b1, 0.f));
        }
    }
}

// ------------------------------------------------------------------
// dst segment-sum -> dstc[pi][128] bf16 in pperm-compact order.
__launch_bounds__(256)
__global__ void dst_sum_k(const unsigned short* __restrict__ feats,
                          const int* __restrict__ t_idx, const int* __restrict__ dst_nodes,
                          const int* __restrict__ dst_rowptr, const int* __restrict__ pperm,
                          unsigned short* __restrict__ dstc) {
    int pi = blockIdx.x * 4 + (threadIdx.x >> 6);
    int lane = threadIdx.x & 63;
    int sub = lane >> 4;
    int fl = lane & 15;
    if (pi >= PP) return;
    int p = pperm[pi];
    long t = t_idx[p];
    const unsigned short* base = feats + t * (long)NN * HD;
    int s = dst_rowptr[p], e = dst_rowptr[p + 1];
    float acc[8] = {};
    int i = s + sub;
    int nd_next = (i < e) ? dst_nodes[i] : 0;
    for (; i < e; i += 4) {
        int nd = nd_next;
        int in = i + 4;
        if (in < e) nd_next = dst_nodes[in];
        us8 v = *(const us8*)&base[(size_t)nd * HD + fl * 8];
#pragma unroll
        for (int j = 0; j < 8; ++j) acc[j] += bf2f(v.v[j]);
    }
#pragma unroll
    for (int m = 16; m < 64; m <<= 1)
#pragma unroll
        for (int j = 0; j < 8; ++j) acc[j] += __shfl_xor(acc[j], m);
    if (sub == 0) {
        us8 o;
#pragma unroll
        for (int j = 0; j < 8; ++j) o.v[j] = f2bf(acc[j]);
        *(us8*)&dstc[(size_t)pi * HD + fl * 8] = o;
    }
}

// ------------------------------------------------------------------
// dec5: barrier-free decoder, wave owns 32 rows x 192 cols.
// A-redundancy 2x (vs dec2's 4x) -> halved LLC gather traffic; unique B per
// block unchanged (repeat read is L1/L2-hit).  w = cw*2 + rw.
__launch_bounds__(256)
__global__ void dec5_k(const unsigned short* __restrict__ feats,
                       const unsigned short* __restrict__ dstc,
                       const int* __restrict__ place_idx, const int* __restrict__ src_idx,
                       const int* __restrict__ t_idx, const int* __restrict__ group_id,
                       const int* __restrict__ pperm,
                       const unsigned short* __restrict__ Wd1t,
                       const float* __restrict__ bd1, const float* __restrict__ Wd2,
                       const float* __restrict__ bd2, float* __restrict__ logprob,
                       float* __restrict__ group_sums) {
    __shared__ float lpart[4][32][2];
    int tid = threadIdx.x;
    int lane = tid & 63, w = tid >> 6;
    int cc = lane & 15, gq = lane >> 4;
    int rw = w & 1, cw = w >> 1;
    int p0 = blockIdx.x * 64;

    // 6 row-base pointers per lane (3 sections x 2 m-subtiles)
    const unsigned short* base[3][2];
#pragma unroll
    for (int s = 0; s < 2; ++s) {
        int pic = min(p0 + (rw * 2 + s) * 16 + cc, PP - 1);
        int pc = pperm[pic];
        long t = t_idx[pc];
        base[0][s] = feats + ((t * NN + place_idx[pc]) * (long)HD);
        base[1][s] = feats + ((t * NN + src_idx[pc]) * (long)HD);
        base[2][s] = dstc + (size_t)pic * HD;
    }

    f32x4 acc[2][12];
#pragma unroll
    for (int s = 0; s < 2; ++s)
#pragma unroll
        for (int t = 0; t < 12; ++t) acc[s][t] = (f32x4){0.f, 0.f, 0.f, 0.f};

    const unsigned short* bbase = Wd1t + ((long)(cw * 192 + cc) * 384 + gq * 8);

    short8 a_n[2];
#pragma unroll
    for (int s = 0; s < 2; ++s) a_n[s] = *(const short8*)(base[0][s] + gq * 8);

#pragma unroll
    for (int kk = 0; kk < 12; ++kk) {
        short8 a_c[2];
#pragma unroll
        for (int s = 0; s < 2; ++s) a_c[s] = a_n[s];
        if (kk < 11) {
            int sec = (kk + 1) >> 2;
            int off = (((kk + 1) * 32) & 127) + gq * 8;
#pragma unroll
            for (int s = 0; s < 2; ++s) a_n[s] = *(const short8*)(base[sec][s] + off);
        }
#pragma unroll
        for (int t = 0; t < 12; ++t) {
            short8 b = *(const short8*)(bbase + (long)t * 16 * 384 + kk * 32);
#pragma unroll
            for (int s = 0; s < 2; ++s)
                acc[s][t] = __builtin_amdgcn_mfma_f32_16x16x32_bf16(a_c[s], b, acc[s][t], 0, 0, 0);
        }
    }

    // epilogue: bias + relu + Wd2 partials, reduce over the 16 cc lanes
    float part[2][4][2] = {};
#pragma unroll
    for (int t = 0; t < 12; ++t) {
        int col = cw * 192 + t * 16 + cc;
        float b1 = bd1[col];
        float w0 = Wd2[col * 2 + 0], w1 = Wd2[col * 2 + 1];
#pragma unroll
        for (int s = 0; s < 2; ++s)
#pragma unroll
            for (int r = 0; r < 4; ++r) {
                float h = fmaxf(acc[s][t][r] + b1, 0.f);
                part[s][r][0] += h * w0;
                part[s][r][1] += h * w1;
            }
    }
#pragma unroll
    for (int m = 1; m < 16; m <<= 1)
#pragma unroll
        for (int s = 0; s < 2; ++s)
#pragma unroll
            for (int r = 0; r < 4; ++r) {
                part[s][r][0] += __shfl_xor(part[s][r][0], m);
                part[s][r][1] += __shfl_xor(part[s][r][1], m);
            }
    if (cc == 0) {
#pragma unroll
        for (int s = 0; s < 2; ++s)
#pragma unroll
            for (int r = 0; r < 4; ++r) {
                int rowl = s * 16 + gq * 4 + r;
                lpart[w][rowl][0] = part[s][r][0];
                lpart[w][rowl][1] = part[s][r][1];
            }
    }
    __syncthreads();
    if (tid < 64) {
        int pi = p0 + tid;
        if (pi < PP) {
            int rw2 = tid >> 5, rl = tid & 31;
            int p = pperm[pi];
            float l0 = lpart[rw2][rl][0] + lpart[2 + rw2][rl][0] + bd2[0];
            float l1 = lpart[rw2][rl][1] + lpart[2 + rw2][rl][1] + bd2[1];
            float m = fmaxf(l0, l1);
            float lse = m + logf(expf(l0 - m) + expf(l1 - m));
            float lp0 = l0 - lse, lp1 = l1 - lse;
            logprob[p * 2 + 0] = lp0;
            logprob[p * 2 + 1] = lp1;
            int g = group_id[p];
            atomicAdd(&group_sums[g * 2 + 0], lp0);
            atomicAdd(&group_sums[g * 2 + 1], lp1);
        }
    }
}

// ------------------------------------------------------------------
// single block: counts total + segmented inclusive cumsum within variants
__global__ void within_total_k(const float* __restrict__ group_sums,
                               const int* __restrict__ var_rowptr,
                               const float* __restrict__ counts,
                               float* __restrict__ within, float* __restrict__ total) {
    __shared__ float buf[256];
    int tid = threadIdx.x;
    float s = 0.f;
    for (int i = tid; i < VV; i += 256) s += counts[i];
    buf[tid] = s;
    __syncthreads();
    for (int off = 128; off > 0; off >>= 1) {
        if (tid < off) buf[tid] += buf[tid + off];
        __syncthreads();
    }
    if (tid == 0) total[0] = buf[0];
    for (int v = tid; v < VV; v += 256) {
        int gs = var_rowptr[v], ge = var_rowptr[v + 1];
        float r0 = 0.f, r1 = 0.f;
        for (int g = gs; g < ge; ++g) {
            r0 += group_sums[2 * g + 0];
            r1 += group_sums[2 * g + 1];
            within[2 * g + 0] = r0;
            within[2 * g + 1] = r1;
        }
    }
}

__global__ void final_k(const float* __restrict__ logprob, const float* __restrict__ within,
                        const int* __restrict__ group_id, const int* __restrict__ vog,
                        const float* __restrict__ counts, const float* __restrict__ total,
                        const int* __restrict__ place_idx, float* __restrict__ outp) {
    int p = blockIdx.x * blockDim.x + threadIdx.x;
    if (p >= PP) return;
    int g = group_id[p];
    int v = vog[g];
    float lc = logf(counts[v]) - logf(total[0]);
    int node = place_idx[p];
    atomicAdd(&outp[node * 2 + 0], logprob[p * 2 + 0] + within[g * 2 + 0] + lc);
    atomicAdd(&outp[node * 2 + 1], logprob[p * 2 + 1] + within[g * 2 + 1] + lc);
}

// ------------------------------------------------------------------
extern "C" void kernel_launch(void* const* d_in, const int* in_sizes, int n_in,
                              void* d_out, int out_size, void* d_ws, size_t ws_size,
                              hipStream_t stream) {
    const float* x          = (const float*)d_in[0];
    const float* W_enc_self = (const float*)d_in[1];
    const float* W_enc_nei  = (const float*)d_in[2];
    const float* b_enc      = (const float*)d_in[3];
    const float* W2_self    = (const float*)d_in[4];
    const float* W2_nei     = (const float*)d_in[5];
    const float* b2         = (const float*)d_in[6];
    const float* Wd1        = (const float*)d_in[7];
    const float* bd1        = (const float*)d_in[8];
    const float* Wd2        = (const float*)d_in[9];
    const float* bd2        = (const float*)d_in[10];
    const float* counts     = (const float*)d_in[11];
    const int* edge_src     = (const int*)d_in[12];
    const int* edge_dst     = (const int*)d_in[13];
    const int* place_idx    = (const int*)d_in[14];
    const int* src_idx      = (const int*)d_in[15];
    const int* t_idx        = (const int*)d_in[16];
    const int* dst_nodes    = (const int*)d_in[17];
    const int* dst_seg      = (const int*)d_in[18];
    const int* group_id     = (const int*)d_in[19];
    const int* variant_of_group = (const int*)d_in[20];
    float* outp = (float*)d_out;

    const int NB = (NN + 255) / 256;   // 196 scan blocks
    const int NBLK = (NN + 3) / 4;     // 12500 agg blocks per pass

    // ---- workspace layout (R10-identical) ----
    unsigned short* feats = (unsigned short*)d_ws;              // 9*N*H bf16
    unsigned short* aggb  = feats + (size_t)(TT + 1) * NN * HD; // N*H
    unsigned short* xb    = aggb + (size_t)NN * HD;             // N*FIN
    unsigned short* dstc  = xb + (size_t)NN * FINN;             // P*H bf16 (pperm-compact)
    unsigned short* wenc_t = dstc + (size_t)PP * HD;            // 128*128
    unsigned short* w2_t   = wenc_t + HD * 2 * FINN;            // 128*256
    unsigned short* wd1t   = w2_t + HD * 2 * HD;                // 384*384
    int* zr = (int*)(wd1t + 384 * 384);                         // zero-region start
    int* csr_counts   = zr;                                     // N
    int* csr_cursor   = csr_counts + NN;                        // N
    float* group_sums = (float*)(csr_cursor + NN);              // 2G
    int* hist9        = (int*)(group_sums + 2 * GG);            // 9
    int* cursor9      = hist9 + 9;                              // 9
    size_t zero_words = (size_t)NN + NN + 2 * GG + 18;
    int* bsum       = cursor9 + 9;                              // 256
    int* boff       = bsum + 256;                               // 256
    int* boff9      = boff + 256;                               // 9 (+pad 7)
    int* csr_rowptr = boff9 + 16;                               // N+1
    int* dst_rowptr = csr_rowptr + (NN + 1);                    // P+1
    int* var_rowptr = dst_rowptr + (PP + 1);                    // V+1
    int* csr_src    = var_rowptr + (VV + 1);                    // E
    int* pperm      = csr_src + EE;                             // P
    float* logprob  = (float*)(pperm + PP);                     // 2P
    float* within   = logprob + 2 * PP;                         // 2G
    float* total_counts = within + 2 * GG;                      // 1

    hipMemsetAsync(zr, 0, zero_words * 4, stream);
    hipMemsetAsync(d_out, 0, (size_t)out_size * sizeof(float), stream);

    // ---- fused prep + CSR builds + t-bucket permutation ----
    prep_k<<<(NN * FINN + 255) / 256, 256, 0, stream>>>(x, W_enc_self, W_enc_nei, W2_self,
                                                        W2_nei, Wd1, xb, wenc_t, w2_t, wd1t);
    count_k<<<(EE + 255) / 256, 256, 0, stream>>>(edge_dst, csr_counts, EE);
    blk_sum_k<<<NB, 256, 0, stream>>>(csr_counts, NN, bsum);
    scan_small_k<<<1, 256, 0, stream>>>(bsum, NB, boff);
    rowptr_fill_k<<<NB, 256, 0, stream>>>(csr_counts, boff, NN, csr_rowptr, EE);
    fill_csr_k<<<(EE + 255) / 256, 256, 0, stream>>>(edge_src, edge_dst, csr_rowptr,
                                                     csr_cursor, csr_src, EE);
    lb_rowptr_k<<<(PP + 256) / 256, 256, 0, stream>>>(dst_seg, DD, dst_rowptr, PP);
    lb_rowptr_k<<<(VV + 256) / 256, 256, 0, stream>>>(variant_of_group, GG, var_rowptr, VV);
    hist9_k<<<(PP + 255) / 256, 256, 0, stream>>>(t_idx, hist9);
    scan9_k<<<1, 64, 0, stream>>>(hist9, boff9);
    bucket_perm_k<<<(PP + 255) / 256, 256, 0, stream>>>(t_idx, boff9, cursor9, pperm);

    // ---- 9 message-passing rounds (pass-sequential column-sliced agg) ----
    for (int r = 0; r <= TT; ++r) {
        const unsigned short* hin = (r == 0) ? xb : feats + (size_t)(r - 1) * NN * HD;
        unsigned short* hout = feats + (size_t)r * NN * HD;
        if (r == 0) {
            for (int p = 0; p < FINN / 32; ++p)
                aggs_k<FINN><<<NBLK, 256, 0, stream>>>(hin, csr_rowptr, csr_src, aggb, p);
            mp_mfma_k<<<(NN + 63) / 64, 256, 0, stream>>>(hin, aggb, wenc_t, b_enc, hout, FINN);
        } else {
            for (int p = 0; p < HD / 32; ++p)
                aggs_k<HD><<<NBLK, 256, 0, stream>>>(hin, csr_rowptr, csr_src, aggb, p);
            mp_mfma_k<<<(NN + 63) / 64, 256, 0, stream>>>(hin, aggb, w2_t, b2, hout, HD);
        }
    }

    // ---- dst segment-sum (pperm-compact) + dec5 decoder ----
    dst_sum_k<<<(PP + 3) / 4, 256, 0, stream>>>(feats, t_idx, dst_nodes, dst_rowptr, pperm, dstc);
    dec5_k<<<(PP + 63) / 64, 256, 0, stream>>>(feats, dstc, place_idx, src_idx, t_idx,
                                               group_id, pperm, wd1t, bd1, Wd2, bd2,
                                               logprob, group_sums);

    // ---- tail ----
    within_total_k<<<1, 256, 0, stream>>>(group_sums, var_rowptr, counts, within, total_counts);
    final_k<<<(PP + 255) / 256, 256, 0, stream>>>(logprob, within, group_id, variant_of_group,
                                                  counts, total_counts, place_idx, outp);
}

// Round 12
// 1172.584 us; speedup vs baseline: 1.5415x; 1.5415x over previous
//
#include <hip/hip_runtime.h>
#include <math.h>

#define NN 50000
#define FINN 64
#define HD 128
#define EE 800000
#define TT 8
#define PP 250000
#define DD 500000
#define GG 20000
#define VV 2000
#define OO 2

typedef short short8 __attribute__((ext_vector_type(8)));
typedef float f32x4 __attribute__((ext_vector_type(4)));

__device__ __forceinline__ unsigned short f2bf(float f) {
    unsigned int u = __float_as_uint(f);
    u += 0x7fffu + ((u >> 16) & 1u);   // round-to-nearest-even
    return (unsigned short)(u >> 16);
}
__device__ __forceinline__ float bf2f(unsigned short u) {
    return __uint_as_float(((unsigned int)u) << 16);
}

struct us8 { unsigned short v[8]; };

// ------------------------------------------------------------------
__global__ void count_k(const int* __restrict__ idx, int* __restrict__ counts, int n) {
    int i = blockIdx.x * blockDim.x + threadIdx.x;
    if (i < n) atomicAdd(&counts[idx[i]], 1);
}

// ---- 3-phase parallel exclusive scan for edge CSR rowptr ----
__global__ void blk_sum_k(const int* __restrict__ counts, int n, int* __restrict__ bsum) {
    __shared__ int buf[256];
    int t = threadIdx.x, i = blockIdx.x * 256 + t;
    buf[t] = (i < n) ? counts[i] : 0;
    __syncthreads();
    for (int off = 128; off > 0; off >>= 1) {
        if (t < off) buf[t] += buf[t + off];
        __syncthreads();
    }
    if (t == 0) bsum[blockIdx.x] = buf[0];
}

__global__ void scan_small_k(const int* __restrict__ bsum, int nb, int* __restrict__ boff) {
    __shared__ int buf[256];
    int t = threadIdx.x;
    int v = (t < nb) ? bsum[t] : 0;
    buf[t] = v;
    __syncthreads();
    for (int off = 1; off < 256; off <<= 1) {
        int u = (t >= off) ? buf[t - off] : 0;
        __syncthreads();
        buf[t] += u;
        __syncthreads();
    }
    if (t < nb) boff[t] = buf[t] - v;
}

__global__ void rowptr_fill_k(const int* __restrict__ counts, const int* __restrict__ boff,
                              int n, int* __restrict__ rowptr, int total) {
    __shared__ int buf[256];
    int t = threadIdx.x, i = blockIdx.x * 256 + t;
    int v = (i < n) ? counts[i] : 0;
    buf[t] = v;
    __syncthreads();
    for (int off = 1; off < 256; off <<= 1) {
        int u = (t >= off) ? buf[t - off] : 0;
        __syncthreads();
        buf[t] += u;
        __syncthreads();
    }
    if (i < n) rowptr[i] = boff[blockIdx.x] + buf[t] - v;
    if (i == 0) rowptr[n] = total;
}

// rowptr for SORTED arrays: rowptr[i] = lower_bound(arr, i), i in [0, m]
__global__ void lb_rowptr_k(const int* __restrict__ arr, int n, int* __restrict__ rowptr, int m) {
    int i = blockIdx.x * blockDim.x + threadIdx.x;
    if (i > m) return;
    int lo = 0, hi = n;
    while (lo < hi) {
        int mid = (lo + hi) >> 1;
        if (arr[mid] < i) lo = mid + 1; else hi = mid;
    }
    rowptr[i] = lo;
}

__global__ void fill_csr_k(const int* __restrict__ esrc, const int* __restrict__ edst,
                           const int* __restrict__ rowptr, int* __restrict__ cursor,
                           int* __restrict__ outi, int n) {
    int e = blockIdx.x * blockDim.x + threadIdx.x;
    if (e < n) {
        int d = edst[e];
        int pos = atomicAdd(&cursor[d], 1);
        outi[rowptr[d] + pos] = esrc[e];
    }
}

// ------------------------------------------------------------------
// t-bucket permutation
__global__ void hist9_k(const int* __restrict__ t_idx, int* __restrict__ hist) {
    __shared__ int l[9];
    if (threadIdx.x < 9) l[threadIdx.x] = 0;
    __syncthreads();
    int p = blockIdx.x * 256 + threadIdx.x;
    if (p < PP) atomicAdd(&l[t_idx[p]], 1);
    __syncthreads();
    if (threadIdx.x < 9) atomicAdd(&hist[threadIdx.x], l[threadIdx.x]);
}

__global__ void scan9_k(const int* __restrict__ hist, int* __restrict__ boff9) {
    if (threadIdx.x == 0) {
        int a = 0;
        for (int i = 0; i < 9; ++i) { boff9[i] = a; a += hist[i]; }
    }
}

__global__ void bucket_perm_k(const int* __restrict__ t_idx, const int* __restrict__ boff9,
                              int* __restrict__ cursor9, int* __restrict__ pperm) {
    __shared__ int lcnt[9];
    __shared__ int lbase[9];
    int tid = threadIdx.x;
    int p = blockIdx.x * 256 + tid;
    if (tid < 9) lcnt[tid] = 0;
    __syncthreads();
    int t = 0, lr = 0;
    bool ok = p < PP;
    if (ok) {
        t = t_idx[p];
        lr = atomicAdd(&lcnt[t], 1);
    }
    __syncthreads();
    if (tid < 9) lbase[tid] = atomicAdd(&cursor9[tid], lcnt[tid]);
    __syncthreads();
    if (ok) pperm[boff9[t] + lbase[t] + lr] = p;
}

// ------------------------------------------------------------------
// fused prep: x->bf16, both mp weight transposes, Wd1 transpose
__global__ void prep_k(const float* __restrict__ x,
                       const float* __restrict__ Wes, const float* __restrict__ Wen,
                       const float* __restrict__ W2s, const float* __restrict__ W2n,
                       const float* __restrict__ Wd1,
                       unsigned short* __restrict__ xb, unsigned short* __restrict__ wenc_t,
                       unsigned short* __restrict__ w2_t, unsigned short* __restrict__ wd1t) {
    int i = blockIdx.x * 256 + threadIdx.x;
    if (i < NN * FINN) xb[i] = f2bf(x[i]);
    if (i < HD * 2 * FINN) {
        int c = i / (2 * FINN), k = i - c * (2 * FINN);
        wenc_t[i] = f2bf((k < FINN) ? Wes[k * HD + c] : Wen[(k - FINN) * HD + c]);
    }
    if (i < HD * 2 * HD) {
        int c = i / (2 * HD), k = i - c * (2 * HD);
        w2_t[i] = f2bf((k < HD) ? W2s[k * HD + c] : W2n[(k - HD) * HD + c]);
    }
    if (i < 384 * 384) {
        int n = i / 384, k = i - n * 384;
        wd1t[i] = f2bf(Wd1[k * 384 + n]);
    }
}

// ------------------------------------------------------------------
// mean-aggregation, bf16 (R8-proven): 1 wave per node; 64/LPR sub-chains,
// depth-2 pipelined (2 row loads in flight per chain).
template <int KIN>
__launch_bounds__(256)
__global__ void agg2_k(const unsigned short* __restrict__ h, const int* __restrict__ rowptr,
                       const int* __restrict__ csr_src, unsigned short* __restrict__ aggout) {
    constexpr int LPR = KIN >> 3;      // lanes per row (ushort8 each)
    constexpr int EPW = 64 / LPR;      // chains per wave
    int node = blockIdx.x * 4 + (threadIdx.x >> 6);
    int lane = threadIdx.x & 63;
    int sub = lane / LPR;
    int fl = lane % LPR;
    if (node >= NN) return;
    int s = rowptr[node], e = rowptr[node + 1];
    float acc[8] = {};
    int i = s + sub;
    int iB = i + EPW;
    int srcA = (i < e) ? csr_src[i] : 0;
    int srcB = (iB < e) ? csr_src[iB] : 0;
    while (i < e) {
        bool hB = iB < e;
        us8 vA = *(const us8*)&h[(size_t)srcA * KIN + fl * 8];
        us8 vB;
        if (hB) vB = *(const us8*)&h[(size_t)srcB * KIN + fl * 8];
        int iN = iB + EPW, iN2 = iN + EPW;
        srcA = (iN < e) ? csr_src[iN] : 0;
        srcB = (iN2 < e) ? csr_src[iN2] : 0;
#pragma unroll
        for (int j = 0; j < 8; ++j) acc[j] += bf2f(vA.v[j]);
        if (hB) {
#pragma unroll
            for (int j = 0; j < 8; ++j) acc[j] += bf2f(vB.v[j]);
        }
        i = iN; iB = iN2;
    }
#pragma unroll
    for (int m = LPR; m < 64; m <<= 1)
#pragma unroll
        for (int j = 0; j < 8; ++j) acc[j] += __shfl_xor(acc[j], m);
    if (sub == 0) {
        float d = fmaxf((float)(e - s), 1.f);
        us8 o;
#pragma unroll
        for (int j = 0; j < 8; ++j) o.v[j] = f2bf(acc[j] / d);
        *(us8*)&aggout[(size_t)node * KIN + fl * 8] = o;
    }
}

// ------------------------------------------------------------------
// h_out = relu([hin | agg] @ Wt^T + b), bf16 MFMA, no LDS.
// 128-thread blocks x 32 rows -> 1563 blocks (vs 782): better CU spread.
__launch_bounds__(128)
__global__ void mp_mfma_k(const unsigned short* __restrict__ hin,
                          const unsigned short* __restrict__ aggin,
                          const unsigned short* __restrict__ Wt,
                          const float* __restrict__ bias,
                          unsigned short* __restrict__ hout, int Kin) {
    int tid = threadIdx.x;
    int lane = tid & 63, w = tid >> 6;
    int cc = lane & 15, g = lane >> 4;
    int K = 2 * Kin;
    int rowA = blockIdx.x * 32 + w * 16 + cc;
    bool rowok = rowA < NN;
    const unsigned short* hrow = hin + (size_t)rowA * Kin;
    const unsigned short* arow = aggin + (size_t)rowA * Kin;

    f32x4 acc[8];
#pragma unroll
    for (int t = 0; t < 8; ++t) acc[t] = (f32x4){0.f, 0.f, 0.f, 0.f};

    for (int k0 = 0; k0 < K; k0 += 32) {
        int k = k0 + g * 8;
        short8 a = {0, 0, 0, 0, 0, 0, 0, 0};
        if (rowok)
            a = *(const short8*)((k < Kin) ? (hrow + k) : (arow + (k - Kin)));
#pragma unroll
        for (int t = 0; t < 8; ++t) {
            short8 b = *(const short8*)&Wt[(size_t)(t * 16 + cc) * K + k];
            acc[t] = __builtin_amdgcn_mfma_f32_16x16x32_bf16(a, b, acc[t], 0, 0, 0);
        }
    }
#pragma unroll
    for (int t = 0; t < 8; ++t) {
        int col = t * 16 + cc;
        float b1 = bias[col];
#pragma unroll
        for (int r = 0; r < 4; ++r) {
            int grow = blockIdx.x * 32 + w * 16 + g * 4 + r;
            if (grow < NN)
                hout[(size_t)grow * HD + col] = f2bf(fmaxf(acc[t][r] + b1, 0.f));
        }
    }
}

// ------------------------------------------------------------------
// dst segment-sum -> dstc[pi][128] bf16 in pperm-compact order.
__launch_bounds__(256)
__global__ void dst_sum_k(const unsigned short* __restrict__ feats,
                          const int* __restrict__ t_idx, const int* __restrict__ dst_nodes,
                          const int* __restrict__ dst_rowptr, const int* __restrict__ pperm,
                          unsigned short* __restrict__ dstc) {
    int pi = blockIdx.x * 4 + (threadIdx.x >> 6);
    int lane = threadIdx.x & 63;
    int sub = lane >> 4;
    int fl = lane & 15;
    if (pi >= PP) return;
    int p = pperm[pi];
    long t = t_idx[p];
    const unsigned short* base = feats + t * (long)NN * HD;
    int s = dst_rowptr[p], e = dst_rowptr[p + 1];
    float acc[8] = {};
    int i = s + sub;
    int nd_next = (i < e) ? dst_nodes[i] : 0;
    for (; i < e; i += 4) {
        int nd = nd_next;
        int in = i + 4;
        if (in < e) nd_next = dst_nodes[in];
        us8 v = *(const us8*)&base[(size_t)nd * HD + fl * 8];
#pragma unroll
        for (int j = 0; j < 8; ++j) acc[j] += bf2f(v.v[j]);
    }
#pragma unroll
    for (int m = 16; m < 64; m <<= 1)
#pragma unroll
        for (int j = 0; j < 8; ++j) acc[j] += __shfl_xor(acc[j], m);
    if (sub == 0) {
        us8 o;
#pragma unroll
        for (int j = 0; j < 8; ++j) o.v[j] = f2bf(acc[j]);
        *(us8*)&dstc[(size_t)pi * HD + fl * 8] = o;
    }
}

// ------------------------------------------------------------------
// barrier-free fused decoder (R8/R10-proven, 264us), pperm-driven;
// dst section reads pperm-compact dstc sequentially.
__launch_bounds__(256)
__global__ void dec2_k(const unsigned short* __restrict__ feats,
                       const unsigned short* __restrict__ dstc,
                       const int* __restrict__ place_idx, const int* __restrict__ src_idx,
                       const int* __restrict__ t_idx, const int* __restrict__ group_id,
                       const int* __restrict__ pperm,
                       const unsigned short* __restrict__ Wd1t,
                       const float* __restrict__ bd1, const float* __restrict__ Wd2,
                       const float* __restrict__ bd2, float* __restrict__ logprob,
                       float* __restrict__ group_sums) {
    __shared__ float lpart[4][64][2];
    int tid = threadIdx.x;
    int lane = tid & 63, w = tid >> 6;
    int cc = lane & 15, gq = lane >> 4;
    int p0 = blockIdx.x * 64;

    // 12 row-base pointers per lane (3 sections x 4 m-subtiles)
    const unsigned short* base[3][4];
#pragma unroll
    for (int s = 0; s < 4; ++s) {
        int pic = min(p0 + s * 16 + cc, PP - 1);
        int pc = pperm[pic];
        long t = t_idx[pc];
        base[0][s] = feats + ((t * NN + place_idx[pc]) * (long)HD);
        base[1][s] = feats + ((t * NN + src_idx[pc]) * (long)HD);
        base[2][s] = dstc + (size_t)pic * HD;
    }

    f32x4 acc[4][6];
#pragma unroll
    for (int s = 0; s < 4; ++s)
#pragma unroll
        for (int t = 0; t < 6; ++t) acc[s][t] = (f32x4){0.f, 0.f, 0.f, 0.f};

    const unsigned short* bbase = Wd1t + ((long)(w * 96 + cc) * 384 + gq * 8);

    short8 a_n[4];
#pragma unroll
    for (int s = 0; s < 4; ++s) a_n[s] = *(const short8*)(base[0][s] + gq * 8);

#pragma unroll
    for (int kk = 0; kk < 12; ++kk) {
        short8 a_c[4];
#pragma unroll
        for (int s = 0; s < 4; ++s) a_c[s] = a_n[s];
        if (kk < 11) {
            int sec = (kk + 1) >> 2;
            int off = (((kk + 1) * 32) & 127) + gq * 8;
#pragma unroll
            for (int s = 0; s < 4; ++s) a_n[s] = *(const short8*)(base[sec][s] + off);
        }
#pragma unroll
        for (int t = 0; t < 6; ++t) {
            short8 b = *(const short8*)(bbase + (long)t * 16 * 384 + kk * 32);
#pragma unroll
            for (int s = 0; s < 4; ++s)
                acc[s][t] = __builtin_amdgcn_mfma_f32_16x16x32_bf16(a_c[s], b, acc[s][t], 0, 0, 0);
        }
    }

    // epilogue: bias + relu + Wd2 partials, reduce over the 16 cc lanes
    float part[4][4][2] = {};
#pragma unroll
    for (int t = 0; t < 6; ++t) {
        int col = w * 96 + t * 16 + cc;
        float b1 = bd1[col];
        float w0 = Wd2[col * 2 + 0], w1 = Wd2[col * 2 + 1];
#pragma unroll
        for (int s = 0; s < 4; ++s)
#pragma unroll
            for (int r = 0; r < 4; ++r) {
                float h = fmaxf(acc[s][t][r] + b1, 0.f);
                part[s][r][0] += h * w0;
                part[s][r][1] += h * w1;
            }
    }
#pragma unroll
    for (int m = 1; m < 16; m <<= 1)
#pragma unroll
        for (int s = 0; s < 4; ++s)
#pragma unroll
            for (int r = 0; r < 4; ++r) {
                part[s][r][0] += __shfl_xor(part[s][r][0], m);
                part[s][r][1] += __shfl_xor(part[s][r][1], m);
            }
    if (cc == 0) {
#pragma unroll
        for (int s = 0; s < 4; ++s)
#pragma unroll
            for (int r = 0; r < 4; ++r) {
                int row = s * 16 + gq * 4 + r;
                lpart[w][row][0] = part[s][r][0];
                lpart[w][row][1] = part[s][r][1];
            }
    }
    __syncthreads();
    if (tid < 64) {
        int pi = p0 + tid;
        if (pi < PP) {
            int p = pperm[pi];
            float l0 = lpart[0][tid][0] + lpart[1][tid][0] + lpart[2][tid][0] + lpart[3][tid][0] + bd2[0];
            float l1 = lpart[0][tid][1] + lpart[1][tid][1] + lpart[2][tid][1] + lpart[3][tid][1] + bd2[1];
            float m = fmaxf(l0, l1);
            float lse = m + logf(expf(l0 - m) + expf(l1 - m));
            float lp0 = l0 - lse, lp1 = l1 - lse;
            logprob[p * 2 + 0] = lp0;
            logprob[p * 2 + 1] = lp1;
            int g = group_id[p];
            atomicAdd(&group_sums[g * 2 + 0], lp0);
            atomicAdd(&group_sums[g * 2 + 1], lp1);
        }
    }
}

// ------------------------------------------------------------------
// single block: counts total + segmented inclusive cumsum within variants
__global__ void within_total_k(const float* __restrict__ group_sums,
                               const int* __restrict__ var_rowptr,
                               const float* __restrict__ counts,
                               float* __restrict__ within, float* __restrict__ total) {
    __shared__ float buf[256];
    int tid = threadIdx.x;
    float s = 0.f;
    for (int i = tid; i < VV; i += 256) s += counts[i];
    buf[tid] = s;
    __syncthreads();
    for (int off = 128; off > 0; off >>= 1) {
        if (tid < off) buf[tid] += buf[tid + off];
        __syncthreads();
    }
    if (tid == 0) total[0] = buf[0];
    for (int v = tid; v < VV; v += 256) {
        int gs = var_rowptr[v], ge = var_rowptr[v + 1];
        float r0 = 0.f, r1 = 0.f;
        for (int g = gs; g < ge; ++g) {
            r0 += group_sums[2 * g + 0];
            r1 += group_sums[2 * g + 1];
            within[2 * g + 0] = r0;
            within[2 * g + 1] = r1;
        }
    }
}

__global__ void final_k(const float* __restrict__ logprob, const float* __restrict__ within,
                        const int* __restrict__ group_id, const int* __restrict__ vog,
                        const float* __restrict__ counts, const float* __restrict__ total,
                        const int* __restrict__ place_idx, float* __restrict__ outp) {
    int p = blockIdx.x * blockDim.x + threadIdx.x;
    if (p >= PP) return;
    int g = group_id[p];
    int v = vog[g];
    float lc = logf(counts[v]) - logf(total[0]);
    int node = place_idx[p];
    atomicAdd(&outp[node * 2 + 0], logprob[p * 2 + 0] + within[g * 2 + 0] + lc);
    atomicAdd(&outp[node * 2 + 1], logprob[p * 2 + 1] + within[g * 2 + 1] + lc);
}

// ------------------------------------------------------------------
extern "C" void kernel_launch(void* const* d_in, const int* in_sizes, int n_in,
                              void* d_out, int out_size, void* d_ws, size_t ws_size,
                              hipStream_t stream) {
    const float* x          = (const float*)d_in[0];
    const float* W_enc_self = (const float*)d_in[1];
    const float* W_enc_nei  = (const float*)d_in[2];
    const float* b_enc      = (const float*)d_in[3];
    const float* W2_self    = (const float*)d_in[4];
    const float* W2_nei     = (const float*)d_in[5];
    const float* b2         = (const float*)d_in[6];
    const float* Wd1        = (const float*)d_in[7];
    const float* bd1        = (const float*)d_in[8];
    const float* Wd2        = (const float*)d_in[9];
    const float* bd2        = (const float*)d_in[10];
    const float* counts     = (const float*)d_in[11];
    const int* edge_src     = (const int*)d_in[12];
    const int* edge_dst     = (const int*)d_in[13];
    const int* place_idx    = (const int*)d_in[14];
    const int* src_idx      = (const int*)d_in[15];
    const int* t_idx        = (const int*)d_in[16];
    const int* dst_nodes    = (const int*)d_in[17];
    const int* dst_seg      = (const int*)d_in[18];
    const int* group_id     = (const int*)d_in[19];
    const int* variant_of_group = (const int*)d_in[20];
    float* outp = (float*)d_out;

    const int NB = (NN + 255) / 256;   // 196 scan blocks

    // ---- workspace layout (R10-identical) ----
    unsigned short* feats = (unsigned short*)d_ws;              // 9*N*H bf16
    unsigned short* aggb  = feats + (size_t)(TT + 1) * NN * HD; // N*H
    unsigned short* xb    = aggb + (size_t)NN * HD;             // N*FIN
    unsigned short* dstc  = xb + (size_t)NN * FINN;             // P*H bf16 (pperm-compact)
    unsigned short* wenc_t = dstc + (size_t)PP * HD;            // 128*128
    unsigned short* w2_t   = wenc_t + HD * 2 * FINN;            // 128*256
    unsigned short* wd1t   = w2_t + HD * 2 * HD;                // 384*384
    int* zr = (int*)(wd1t + 384 * 384);                         // zero-region start
    int* csr_counts   = zr;                                     // N
    int* csr_cursor   = csr_counts + NN;                        // N
    float* group_sums = (float*)(csr_cursor + NN);              // 2G
    int* hist9        = (int*)(group_sums + 2 * GG);            // 9
    int* cursor9      = hist9 + 9;                              // 9
    size_t zero_words = (size_t)NN + NN + 2 * GG + 18;
    int* bsum       = cursor9 + 9;                              // 256
    int* boff       = bsum + 256;                               // 256
    int* boff9      = boff + 256;                               // 9 (+pad 7)
    int* csr_rowptr = boff9 + 16;                               // N+1
    int* dst_rowptr = csr_rowptr + (NN + 1);                    // P+1
    int* var_rowptr = dst_rowptr + (PP + 1);                    // V+1
    int* csr_src    = var_rowptr + (VV + 1);                    // E
    int* pperm      = csr_src + EE;                             // P
    float* logprob  = (float*)(pperm + PP);                     // 2P
    float* within   = logprob + 2 * PP;                         // 2G
    float* total_counts = within + 2 * GG;                      // 1

    hipMemsetAsync(zr, 0, zero_words * 4, stream);
    hipMemsetAsync(d_out, 0, (size_t)out_size * sizeof(float), stream);

    // ---- fused prep + CSR builds + t-bucket permutation ----
    prep_k<<<(NN * FINN + 255) / 256, 256, 0, stream>>>(x, W_enc_self, W_enc_nei, W2_self,
                                                        W2_nei, Wd1, xb, wenc_t, w2_t, wd1t);
    count_k<<<(EE + 255) / 256, 256, 0, stream>>>(edge_dst, csr_counts, EE);
    blk_sum_k<<<NB, 256, 0, stream>>>(csr_counts, NN, bsum);
    scan_small_k<<<1, 256, 0, stream>>>(bsum, NB, boff);
    rowptr_fill_k<<<NB, 256, 0, stream>>>(csr_counts, boff, NN, csr_rowptr, EE);
    fill_csr_k<<<(EE + 255) / 256, 256, 0, stream>>>(edge_src, edge_dst, csr_rowptr,
                                                     csr_cursor, csr_src, EE);
    lb_rowptr_k<<<(PP + 256) / 256, 256, 0, stream>>>(dst_seg, DD, dst_rowptr, PP);
    lb_rowptr_k<<<(VV + 256) / 256, 256, 0, stream>>>(variant_of_group, GG, var_rowptr, VV);
    hist9_k<<<(PP + 255) / 256, 256, 0, stream>>>(t_idx, hist9);
    scan9_k<<<1, 64, 0, stream>>>(hist9, boff9);
    bucket_perm_k<<<(PP + 255) / 256, 256, 0, stream>>>(t_idx, boff9, cursor9, pperm);

    // ---- 9 message-passing rounds (R8-proven agg2 + wider-grid mp) ----
    for (int r = 0; r <= TT; ++r) {
        const unsigned short* hin = (r == 0) ? xb : feats + (size_t)(r - 1) * NN * HD;
        unsigned short* hout = feats + (size_t)r * NN * HD;
        if (r == 0) {
            agg2_k<FINN><<<(NN + 3) / 4, 256, 0, stream>>>(hin, csr_rowptr, csr_src, aggb);
            mp_mfma_k<<<(NN + 31) / 32, 128, 0, stream>>>(hin, aggb, wenc_t, b_enc, hout, FINN);
        } else {
            agg2_k<HD><<<(NN + 3) / 4, 256, 0, stream>>>(hin, csr_rowptr, csr_src, aggb);
            mp_mfma_k<<<(NN + 31) / 32, 128, 0, stream>>>(hin, aggb, w2_t, b2, hout, HD);
        }
    }

    // ---- dst segment-sum (pperm-compact) + proven dec2 decoder ----
    dst_sum_k<<<(PP + 3) / 4, 256, 0, stream>>>(feats, t_idx, dst_nodes, dst_rowptr, pperm, dstc);
    dec2_k<<<(PP + 63) / 64, 256, 0, stream>>>(feats, dstc, place_idx, src_idx, t_idx,
                                               group_id, pperm, wd1t, bd1, Wd2, bd2,
                                               logprob, group_sums);

    // ---- tail ----
    within_total_k<<<1, 256, 0, stream>>>(group_sums, var_rowptr, counts, within, total_counts);
    final_k<<<(PP + 255) / 256, 256, 0, stream>>>(logprob, within, group_id, variant_of_group,
                                                  counts, total_counts, place_idx, outp);
}